// Round 3
// baseline (1265.895 us; speedup 1.0000x reference)
//
#include <hip/hip_runtime.h>

#define DIV_UP(a,b) (((a)+(b)-1)/(b))

// bucket = tgt >> 7  (128 nodes per bucket)
constexpr int BSHIFT = 7;
constexpr int BNODES = 128;

// ---------------- CSR build via bucket counting sort ----------------
__global__ void zero_int_k(int* p, int n) {
    int i = blockIdx.x * blockDim.x + threadIdx.x;
    if (i < n) p[i] = 0;
}

__global__ void bucket_hist_k(const int* __restrict__ col, int* __restrict__ bhist, int E, int nb) {
    __shared__ int lh[1024];
    for (int i = threadIdx.x; i < 1024; i += blockDim.x) lh[i] = 0;
    __syncthreads();
    int stride = gridDim.x * blockDim.x;
    for (int e = blockIdx.x * blockDim.x + threadIdx.x; e < E; e += stride)
        atomicAdd(&lh[col[e] >> BSHIFT], 1);
    __syncthreads();
    for (int i = threadIdx.x; i < nb; i += blockDim.x) {
        int v = lh[i];
        if (v) atomicAdd(&bhist[i], v);
    }
}

// exclusive scan of nb (<=1024) bucket counts -> bcur
__global__ void bucket_scan_k(const int* __restrict__ bhist, int* __restrict__ bcur, int nb) {
    __shared__ int lds[256];
    int base = threadIdx.x * 4;
    int v[4]; int s = 0;
#pragma unroll
    for (int j = 0; j < 4; j++) { v[j] = (base + j < nb) ? bhist[base + j] : 0; s += v[j]; }
    lds[threadIdx.x] = s; __syncthreads();
    for (int off = 1; off < 256; off <<= 1) {
        int t = (threadIdx.x >= off) ? lds[threadIdx.x - off] : 0;
        __syncthreads();
        lds[threadIdx.x] += t;
        __syncthreads();
    }
    int excl = lds[threadIdx.x] - s;
#pragma unroll
    for (int j = 0; j < 4; j++) {
        if (base + j < nb) bcur[base + j] = excl;
        excl += v[j];
    }
}

// partition edges into buckets; pack (src<<7)|(tgt&127) in 4B (src<2^17, 7 low bits)
__global__ void partition_k(const int* __restrict__ row, const int* __restrict__ col,
                            int* __restrict__ bcur, int* __restrict__ part, int E) {
    int stride = gridDim.x * blockDim.x;
    for (int e = blockIdx.x * blockDim.x + threadIdx.x; e < E; e += stride) {
        int r = row[e], c = col[e];
        int p = atomicAdd(&bcur[c >> BSHIFT], 1);
        part[p] = (r << BSHIFT) | (c & (BNODES - 1));
    }
}

// one block per bucket: count local degrees, scan, emit dinv/cur, scatter csr
__global__ void csr_build_k(const int* __restrict__ part, const int* __restrict__ bcur,
                            int* __restrict__ cur, float* __restrict__ dinv,
                            int* __restrict__ csr, int N) {
    __shared__ int ldeg[BNODES];
    __shared__ int lofs[BNODES];
    __shared__ int ebounds[2];
    int b = blockIdx.x;
    int tid = threadIdx.x;
    if (tid == 0) { ebounds[0] = b ? bcur[b - 1] : 0; ebounds[1] = bcur[b]; }
    if (tid < BNODES) ldeg[tid] = 0;
    __syncthreads();
    int e0 = ebounds[0], e1 = ebounds[1];
    for (int e = e0 + tid; e < e1; e += blockDim.x)
        atomicAdd(&ldeg[part[e] & (BNODES - 1)], 1);
    __syncthreads();
    if (tid < BNODES) lofs[tid] = ldeg[tid];
    __syncthreads();
    for (int off = 1; off < BNODES; off <<= 1) {
        int t = (tid >= off && tid < BNODES) ? lofs[tid - off] : 0;
        __syncthreads();
        if (tid < BNODES) lofs[tid] += t;
        __syncthreads();
    }
    if (tid < BNODES) {
        int node = b * BNODES + tid;
        int d = ldeg[tid];
        int incl = lofs[tid];
        if (node < N) {
            cur[node] = e0 + incl;                       // inclusive end
            dinv[node] = rsqrtf(1.0f + (float)d);        // +1 self loop
        }
        ldeg[tid] = e0 + incl - d;                       // becomes write cursor
    }
    __syncthreads();
    for (int e = e0 + tid; e < e1; e += blockDim.x) {
        int v = part[e];
        int p = atomicAdd(&ldeg[v & (BNODES - 1)], 1);
        csr[p] = v >> BSHIFT;
    }
}

// ---------------- gather propagation (inputs pre-scaled by dinv) ----------------
// out_raw = dinv[t] * ( hs[t] + sum_{edges} hs[src] )   == (D^-1/2 A_hat D^-1/2 h)[t]
// EPI 0: store out_raw.   EPI 1: store relu(out_raw + b) * dinv[t]  (ready for next layer)
template<int D, int EPI>
__global__ void gather_prop_k(const float* __restrict__ hs, const float* __restrict__ dinv,
                              const int* __restrict__ cur, const int* __restrict__ csr,
                              const float* __restrict__ b, float* __restrict__ out, int n) {
    constexpr int TPN = D / 4;
    int tid = blockIdx.x * blockDim.x + threadIdx.x;
    int node = tid / TPN, t = tid % TPN;
    if (node >= n) return;
    float di = dinv[node];
    float4 acc = reinterpret_cast<const float4*>(hs + (size_t)node * D)[t];
    int e0 = node ? cur[node - 1] : 0;
    int e1 = cur[node];
    int e = e0;
    for (; e + 1 < e1; e += 2) {
        int s0 = csr[e], s1 = csr[e + 1];
        float4 v0 = reinterpret_cast<const float4*>(hs + (size_t)s0 * D)[t];
        float4 v1 = reinterpret_cast<const float4*>(hs + (size_t)s1 * D)[t];
        acc.x += v0.x + v1.x; acc.y += v0.y + v1.y;
        acc.z += v0.z + v1.z; acc.w += v0.w + v1.w;
    }
    if (e < e1) {
        int s0 = csr[e];
        float4 v0 = reinterpret_cast<const float4*>(hs + (size_t)s0 * D)[t];
        acc.x += v0.x; acc.y += v0.y; acc.z += v0.z; acc.w += v0.w;
    }
    acc.x *= di; acc.y *= di; acc.z *= di; acc.w *= di;
    if (EPI == 1) {
        acc.x = fmaxf(acc.x + b[t*4+0], 0.f) * di;
        acc.y = fmaxf(acc.y + b[t*4+1], 0.f) * di;
        acc.z = fmaxf(acc.z + b[t*4+2], 0.f) * di;
        acc.w = fmaxf(acc.w + b[t*4+3], 0.f) * di;
    }
    reinterpret_cast<float4*>(out + (size_t)node * D)[t] = acc;
}

// ---------------- dense skinny matmul: y[n,OUT] = x[n,IN] @ W (+b, relu, *dinv) --------
template<int IN, int OUT, bool RELU, bool BIAS, bool SCALE>
__global__ void matmul_k(const float* __restrict__ x, const float* __restrict__ W,
                         const float* __restrict__ b, const float* __restrict__ dinv,
                         float* __restrict__ y, int n) {
    __shared__ float Ws[IN * OUT];
    __shared__ float bs[OUT];
    for (int i = threadIdx.x; i < IN * OUT; i += blockDim.x) Ws[i] = W[i];
    if (BIAS) for (int i = threadIdx.x; i < OUT; i += blockDim.x) bs[i] = b[i];
    __syncthreads();
    int node = blockIdx.x * blockDim.x + threadIdx.x;
    if (node >= n) return;
    float acc[OUT];
#pragma unroll
    for (int j = 0; j < OUT; j++) acc[j] = 0.f;
    const float4* xr = reinterpret_cast<const float4*>(x + (size_t)node * IN);
#pragma unroll
    for (int k4 = 0; k4 < IN / 4; k4++) {
        float4 v = xr[k4];
#pragma unroll
        for (int j = 0; j < OUT; j++) {
            acc[j] += v.x * Ws[(k4*4+0)*OUT + j] + v.y * Ws[(k4*4+1)*OUT + j]
                    + v.z * Ws[(k4*4+2)*OUT + j] + v.w * Ws[(k4*4+3)*OUT + j];
        }
    }
    float di = SCALE ? dinv[node] : 1.f;
    float* yr = y + (size_t)node * OUT;
#pragma unroll
    for (int j = 0; j < OUT; j++) {
        float v = acc[j] + (BIAS ? bs[j] : 0.f);
        if (RELU) v = fmaxf(v, 0.f);
        if (SCALE) v *= di;
        yr[j] = v;
    }
}

// ---------------- pooling + log_softmax ----------------
__device__ inline unsigned fkey(float x) {
    unsigned u = __float_as_uint(x);
    return (u & 0x80000000u) ? ~u : (u | 0x80000000u);
}
__device__ inline float funkey(unsigned k) {
    unsigned u = (k & 0x80000000u) ? (k & 0x7FFFFFFFu) : ~k;
    return __uint_as_float(u);
}

__global__ void pool_init_k(unsigned* pooled, int total) {
    int i = blockIdx.x * blockDim.x + threadIdx.x;
    if (i < total) pooled[i] = 0u;
}

__global__ void pool_max_k(const float* __restrict__ h4, const float* __restrict__ b4,
                           const int* __restrict__ batch, unsigned* __restrict__ pooled,
                           int n, int num_graphs) {
    __shared__ unsigned lds[128 * 4];
    for (int i = threadIdx.x; i < num_graphs * 4; i += blockDim.x) lds[i] = 0u;
    __syncthreads();
    int i = blockIdx.x * blockDim.x + threadIdx.x;
    if (i < n) {
        int g = batch[i];
        float4 v = reinterpret_cast<const float4*>(h4)[i];
        atomicMax(&lds[g*4+0], fkey(v.x + b4[0]));
        atomicMax(&lds[g*4+1], fkey(v.y + b4[1]));
        atomicMax(&lds[g*4+2], fkey(v.z + b4[2]));
        atomicMax(&lds[g*4+3], fkey(v.w + b4[3]));
    }
    __syncthreads();
    for (int i2 = threadIdx.x; i2 < num_graphs * 4; i2 += blockDim.x) {
        unsigned k = lds[i2];
        if (k) atomicMax(&pooled[i2], k);
    }
}

__global__ void logsoftmax_k(const unsigned* __restrict__ pooled, float* __restrict__ out, int G) {
    int g = blockIdx.x * blockDim.x + threadIdx.x;
    if (g >= G) return;
    float v[4];
#pragma unroll
    for (int j = 0; j < 4; j++) v[j] = funkey(pooled[g*4+j]);
    float m = fmaxf(fmaxf(v[0], v[1]), fmaxf(v[2], v[3]));
    float s = 0.f;
#pragma unroll
    for (int j = 0; j < 4; j++) s += expf(v[j] - m);
    float l = logf(s);
#pragma unroll
    for (int j = 0; j < 4; j++) out[g*4+j] = v[j] - m - l;
}

// ---------------- launch ----------------
extern "C" void kernel_launch(void* const* d_in, const int* in_sizes, int n_in,
                              void* d_out, int out_size, void* d_ws, size_t ws_size,
                              hipStream_t stream) {
    const float* x     = (const float*)d_in[0];
    const int*   ei    = (const int*)d_in[1];
    const int*   batch = (const int*)d_in[2];
    const float* W1 = (const float*)d_in[3];
    const float* b1 = (const float*)d_in[4];
    const float* W2 = (const float*)d_in[5];
    const float* b2 = (const float*)d_in[6];
    const float* W3 = (const float*)d_in[7];
    const float* b3 = (const float*)d_in[8];
    const float* W4 = (const float*)d_in[9];
    const float* b4 = (const float*)d_in[10];

    const int N = in_sizes[2];          // 100000
    const int E = in_sizes[1] / 2;      // 3.2M
    const int G = 128;
    const int* row = ei;
    const int* col = ei + E;
    const int NB = DIV_UP(N, BNODES);   // 782 buckets

    // workspace layout
    float* ws    = (float*)d_ws;
    float* dinv  = ws;                              // N floats
    int*   cur   = (int*)(dinv + N);                // N ints (inclusive seg ends)
    int*   bhist = cur + N;                         // 1024 ints
    int*   bcur  = bhist + 1024;                    // 1024 ints
    int*   csr   = bcur + 1024;                     // E ints
    float* f16a  = (float*)(csr + E);               // N*16
    float* f16b  = f16a + (size_t)N * 16;           // N*16
    float* f32a  = f16b + (size_t)N * 16;           // N*32
    float* f32b  = f32a + (size_t)N * 32;           // N*32
    unsigned* pooled = (unsigned*)(f32b + (size_t)N * 32);  // 512
    // part aliases f32a/f32b region (dead before any f32 use); E=3.2M <= 64N=6.4M
    int* part = (int*)f32a;
    float* f64 = f16a;                              // 64N spans f16a..f32a end
    float* f4a = f32b;                              // after L3 matmul, f32b free
    float* f4b = f32b + (size_t)N * 4;

    const int B = 256;
    const int gridN = DIV_UP(N, B);

    // CSR build: hist -> scan -> partition -> per-bucket finalize (also emits dinv)
    zero_int_k<<<DIV_UP(1024, B), B, 0, stream>>>(bhist, 1024);
    bucket_hist_k<<<256, B, 0, stream>>>(col, bhist, E, NB);
    bucket_scan_k<<<1, 256, 0, stream>>>(bhist, bcur, NB);
    partition_k<<<4096, B, 0, stream>>>(row, col, bcur, part, E);
    csr_build_k<<<NB, B, 0, stream>>>(part, bcur, cur, dinv, csr, N);

    // L1: y1 = (x@W1)*dinv -> f16b ; gather+bias+relu+scale -> f16a  (f32a still = part? no: part dead after csr_build)
    matmul_k<128,16,false,false,true><<<gridN, B, 0, stream>>>(x, W1, nullptr, dinv, f16b, N);
    gather_prop_k<16,1><<<DIV_UP(N*4, B), B, 0, stream>>>(f16b, dinv, cur, csr, b1, f16a, N);

    // L2: gather f16a -> f16b (raw agg) ; matmul 16->32 +b2,relu,*dinv -> f32a
    gather_prop_k<16,0><<<DIV_UP(N*4, B), B, 0, stream>>>(f16a, dinv, cur, csr, nullptr, f16b, N);
    matmul_k<16,32,true,true,true><<<gridN, B, 0, stream>>>(f16b, W2, b2, dinv, f32a, N);

    // L3: gather f32a -> f32b ; matmul 32->64 +b3,relu,*dinv -> f64 (= f16a..f32a)
    gather_prop_k<32,0><<<DIV_UP(N*8, B), B, 0, stream>>>(f32a, dinv, cur, csr, nullptr, f32b, N);
    matmul_k<32,64,true,true,true><<<gridN, B, 0, stream>>>(f32b, W3, b3, dinv, f64, N);

    // L4: y4 = h3s@W4 (already dinv-scaled input) -> f4a ; gather raw -> f4b
    matmul_k<64,4,false,false,false><<<gridN, B, 0, stream>>>(f64, W4, nullptr, nullptr, f4a, N);
    gather_prop_k<4,0><<<DIV_UP(N, B), B, 0, stream>>>(f4a, dinv, cur, csr, nullptr, f4b, N);

    // pool (adds b4) + log_softmax
    pool_init_k<<<DIV_UP(G*4, B), B, 0, stream>>>(pooled, G*4);
    pool_max_k<<<gridN, B, 0, stream>>>(f4b, b4, batch, pooled, N, G);
    logsoftmax_k<<<1, 128, 0, stream>>>(pooled, (float*)d_out, G);
}

// Round 4
// 595.721 us; speedup vs baseline: 2.1250x; 2.1250x over previous
//
#include <hip/hip_runtime.h>

#define DIV_UP(a,b) (((a)+(b)-1)/(b))

// bucket = tgt >> 7  (128 nodes per bucket)
constexpr int BSHIFT = 7;
constexpr int BNODES = 128;
constexpr int CHUNK_E = 16384;   // edges per partition block

// ---------------- CSR build via bucket counting sort ----------------
__global__ void zero_int_k(int* p, int n) {
    int i = blockIdx.x * blockDim.x + threadIdx.x;
    if (i < n) p[i] = 0;
}

__global__ void bucket_hist_k(const int* __restrict__ col, int* __restrict__ bhist, int E, int nb) {
    __shared__ int lh[1024];
    for (int i = threadIdx.x; i < 1024; i += blockDim.x) lh[i] = 0;
    __syncthreads();
    int stride = gridDim.x * blockDim.x;
    for (int e = blockIdx.x * blockDim.x + threadIdx.x; e < E; e += stride)
        atomicAdd(&lh[col[e] >> BSHIFT], 1);
    __syncthreads();
    for (int i = threadIdx.x; i < nb; i += blockDim.x) {
        int v = lh[i];
        if (v) atomicAdd(&bhist[i], v);
    }
}

// exclusive scan of nb (<=1024) bucket counts -> bcur
__global__ void bucket_scan_k(const int* __restrict__ bhist, int* __restrict__ bcur, int nb) {
    __shared__ int lds[256];
    int base = threadIdx.x * 4;
    int v[4]; int s = 0;
#pragma unroll
    for (int j = 0; j < 4; j++) { v[j] = (base + j < nb) ? bhist[base + j] : 0; s += v[j]; }
    lds[threadIdx.x] = s; __syncthreads();
    for (int off = 1; off < 256; off <<= 1) {
        int t = (threadIdx.x >= off) ? lds[threadIdx.x - off] : 0;
        __syncthreads();
        lds[threadIdx.x] += t;
        __syncthreads();
    }
    int excl = lds[threadIdx.x] - s;
#pragma unroll
    for (int j = 0; j < 4; j++) {
        if (base + j < nb) bcur[base + j] = excl;
        excl += v[j];
    }
}

// block-batched partition: LDS histogram -> bulk range reservation -> LDS-cursor scatter
// pack (src<<7)|(tgt&127) in 4B (src < 2^17 ok: N=100000 < 131072)
__global__ void partition_k(const int* __restrict__ row, const int* __restrict__ col,
                            int* __restrict__ bcur, int* __restrict__ part, int E, int nb) {
    __shared__ int lh[1024];
    for (int i = threadIdx.x; i < nb; i += blockDim.x) lh[i] = 0;
    __syncthreads();
    int base = blockIdx.x * CHUNK_E;
    int end = min(E, base + CHUNK_E);
    for (int e = base + threadIdx.x; e < end; e += blockDim.x)
        atomicAdd(&lh[col[e] >> BSHIFT], 1);
    __syncthreads();
    for (int i = threadIdx.x; i < nb; i += blockDim.x) {
        int c = lh[i];
        lh[i] = c ? atomicAdd(&bcur[i], c) : 0;   // reserve dense run, LDS keeps base cursor
    }
    __syncthreads();
    for (int e = base + threadIdx.x; e < end; e += blockDim.x) {
        int r = row[e], c = col[e];
        int p = atomicAdd(&lh[c >> BSHIFT], 1);
        part[p] = (r << BSHIFT) | (c & (BNODES - 1));
    }
}

// one block per bucket: count local degrees, scan, emit dinv/cur, scatter csr
__global__ void csr_build_k(const int* __restrict__ part, const int* __restrict__ bcur,
                            int* __restrict__ cur, float* __restrict__ dinv,
                            int* __restrict__ csr, int N) {
    __shared__ int ldeg[BNODES];
    __shared__ int lofs[BNODES];
    __shared__ int ebounds[2];
    int b = blockIdx.x;
    int tid = threadIdx.x;
    if (tid == 0) { ebounds[0] = b ? bcur[b - 1] : 0; ebounds[1] = bcur[b]; }
    if (tid < BNODES) ldeg[tid] = 0;
    __syncthreads();
    int e0 = ebounds[0], e1 = ebounds[1];
    for (int e = e0 + tid; e < e1; e += blockDim.x)
        atomicAdd(&ldeg[part[e] & (BNODES - 1)], 1);
    __syncthreads();
    if (tid < BNODES) lofs[tid] = ldeg[tid];
    __syncthreads();
    for (int off = 1; off < BNODES; off <<= 1) {
        int t = (tid >= off && tid < BNODES) ? lofs[tid - off] : 0;
        __syncthreads();
        if (tid < BNODES) lofs[tid] += t;
        __syncthreads();
    }
    if (tid < BNODES) {
        int node = b * BNODES + tid;
        int d = ldeg[tid];
        int incl = lofs[tid];
        if (node < N) {
            cur[node] = e0 + incl;                       // inclusive end
            dinv[node] = rsqrtf(1.0f + (float)d);        // +1 self loop
        }
        ldeg[tid] = e0 + incl - d;                       // becomes write cursor
    }
    __syncthreads();
    for (int e = e0 + tid; e < e1; e += blockDim.x) {
        int v = part[e];
        int p = atomicAdd(&ldeg[v & (BNODES - 1)], 1);
        csr[p] = v >> BSHIFT;
    }
}

// ---------------- gather propagation (inputs pre-scaled by dinv) ----------------
// out_raw = dinv[t] * ( hs[t] + sum_{edges} hs[src] )   == (D^-1/2 A_hat D^-1/2 h)[t]
// EPI 0: store out_raw.   EPI 1: store relu(out_raw + b) * dinv[t]  (ready for next layer)
template<int D, int EPI>
__global__ void gather_prop_k(const float* __restrict__ hs, const float* __restrict__ dinv,
                              const int* __restrict__ cur, const int* __restrict__ csr,
                              const float* __restrict__ b, float* __restrict__ out, int n) {
    constexpr int TPN = D / 4;
    int tid = blockIdx.x * blockDim.x + threadIdx.x;
    int node = tid / TPN, t = tid % TPN;
    if (node >= n) return;
    float di = dinv[node];
    float4 acc = reinterpret_cast<const float4*>(hs + (size_t)node * D)[t];
    int e0 = node ? cur[node - 1] : 0;
    int e1 = cur[node];
    int e = e0;
    for (; e + 1 < e1; e += 2) {
        int s0 = csr[e], s1 = csr[e + 1];
        float4 v0 = reinterpret_cast<const float4*>(hs + (size_t)s0 * D)[t];
        float4 v1 = reinterpret_cast<const float4*>(hs + (size_t)s1 * D)[t];
        acc.x += v0.x + v1.x; acc.y += v0.y + v1.y;
        acc.z += v0.z + v1.z; acc.w += v0.w + v1.w;
    }
    if (e < e1) {
        int s0 = csr[e];
        float4 v0 = reinterpret_cast<const float4*>(hs + (size_t)s0 * D)[t];
        acc.x += v0.x; acc.y += v0.y; acc.z += v0.z; acc.w += v0.w;
    }
    acc.x *= di; acc.y *= di; acc.z *= di; acc.w *= di;
    if (EPI == 1) {
        acc.x = fmaxf(acc.x + b[t*4+0], 0.f) * di;
        acc.y = fmaxf(acc.y + b[t*4+1], 0.f) * di;
        acc.z = fmaxf(acc.z + b[t*4+2], 0.f) * di;
        acc.w = fmaxf(acc.w + b[t*4+3], 0.f) * di;
    }
    reinterpret_cast<float4*>(out + (size_t)node * D)[t] = acc;
}

// ---------------- dense skinny matmul: y[n,OUT] = x[n,IN] @ W (+b, relu, *dinv) --------
template<int IN, int OUT, bool RELU, bool BIAS, bool SCALE>
__global__ void matmul_k(const float* __restrict__ x, const float* __restrict__ W,
                         const float* __restrict__ b, const float* __restrict__ dinv,
                         float* __restrict__ y, int n) {
    __shared__ float Ws[IN * OUT];
    __shared__ float bs[OUT];
    for (int i = threadIdx.x; i < IN * OUT; i += blockDim.x) Ws[i] = W[i];
    if (BIAS) for (int i = threadIdx.x; i < OUT; i += blockDim.x) bs[i] = b[i];
    __syncthreads();
    int node = blockIdx.x * blockDim.x + threadIdx.x;
    if (node >= n) return;
    float acc[OUT];
#pragma unroll
    for (int j = 0; j < OUT; j++) acc[j] = 0.f;
    const float4* xr = reinterpret_cast<const float4*>(x + (size_t)node * IN);
#pragma unroll
    for (int k4 = 0; k4 < IN / 4; k4++) {
        float4 v = xr[k4];
#pragma unroll
        for (int j = 0; j < OUT; j++) {
            acc[j] += v.x * Ws[(k4*4+0)*OUT + j] + v.y * Ws[(k4*4+1)*OUT + j]
                    + v.z * Ws[(k4*4+2)*OUT + j] + v.w * Ws[(k4*4+3)*OUT + j];
        }
    }
    float di = SCALE ? dinv[node] : 1.f;
    float* yr = y + (size_t)node * OUT;
#pragma unroll
    for (int j = 0; j < OUT; j++) {
        float v = acc[j] + (BIAS ? bs[j] : 0.f);
        if (RELU) v = fmaxf(v, 0.f);
        if (SCALE) v *= di;
        yr[j] = v;
    }
}

// ---------------- pooling + log_softmax ----------------
__device__ inline unsigned fkey(float x) {
    unsigned u = __float_as_uint(x);
    return (u & 0x80000000u) ? ~u : (u | 0x80000000u);
}
__device__ inline float funkey(unsigned k) {
    unsigned u = (k & 0x80000000u) ? (k & 0x7FFFFFFFu) : ~k;
    return __uint_as_float(u);
}

__global__ void pool_init_k(unsigned* pooled, int total) {
    int i = blockIdx.x * blockDim.x + threadIdx.x;
    if (i < total) pooled[i] = 0u;
}

__global__ void pool_max_k(const float* __restrict__ h4, const float* __restrict__ b4,
                           const int* __restrict__ batch, unsigned* __restrict__ pooled,
                           int n, int num_graphs) {
    __shared__ unsigned lds[128 * 4];
    for (int i = threadIdx.x; i < num_graphs * 4; i += blockDim.x) lds[i] = 0u;
    __syncthreads();
    int i = blockIdx.x * blockDim.x + threadIdx.x;
    if (i < n) {
        int g = batch[i];
        float4 v = reinterpret_cast<const float4*>(h4)[i];
        atomicMax(&lds[g*4+0], fkey(v.x + b4[0]));
        atomicMax(&lds[g*4+1], fkey(v.y + b4[1]));
        atomicMax(&lds[g*4+2], fkey(v.z + b4[2]));
        atomicMax(&lds[g*4+3], fkey(v.w + b4[3]));
    }
    __syncthreads();
    for (int i2 = threadIdx.x; i2 < num_graphs * 4; i2 += blockDim.x) {
        unsigned k = lds[i2];
        if (k) atomicMax(&pooled[i2], k);
    }
}

__global__ void logsoftmax_k(const unsigned* __restrict__ pooled, float* __restrict__ out, int G) {
    int g = blockIdx.x * blockDim.x + threadIdx.x;
    if (g >= G) return;
    float v[4];
#pragma unroll
    for (int j = 0; j < 4; j++) v[j] = funkey(pooled[g*4+j]);
    float m = fmaxf(fmaxf(v[0], v[1]), fmaxf(v[2], v[3]));
    float s = 0.f;
#pragma unroll
    for (int j = 0; j < 4; j++) s += expf(v[j] - m);
    float l = logf(s);
#pragma unroll
    for (int j = 0; j < 4; j++) out[g*4+j] = v[j] - m - l;
}

// ---------------- launch ----------------
extern "C" void kernel_launch(void* const* d_in, const int* in_sizes, int n_in,
                              void* d_out, int out_size, void* d_ws, size_t ws_size,
                              hipStream_t stream) {
    const float* x     = (const float*)d_in[0];
    const int*   ei    = (const int*)d_in[1];
    const int*   batch = (const int*)d_in[2];
    const float* W1 = (const float*)d_in[3];
    const float* b1 = (const float*)d_in[4];
    const float* W2 = (const float*)d_in[5];
    const float* b2 = (const float*)d_in[6];
    const float* W3 = (const float*)d_in[7];
    const float* b3 = (const float*)d_in[8];
    const float* W4 = (const float*)d_in[9];
    const float* b4 = (const float*)d_in[10];

    const int N = in_sizes[2];          // 100000
    const int E = in_sizes[1] / 2;      // 3.2M
    const int G = 128;
    const int* row = ei;
    const int* col = ei + E;
    const int NB = DIV_UP(N, BNODES);   // 782 buckets

    // workspace layout
    float* ws    = (float*)d_ws;
    float* dinv  = ws;                              // N floats
    int*   cur   = (int*)(dinv + N);                // N ints (inclusive seg ends)
    int*   bhist = cur + N;                         // 1024 ints
    int*   bcur  = bhist + 1024;                    // 1024 ints
    int*   csr   = bcur + 1024;                     // E ints
    float* f16a  = (float*)(csr + E);               // N*16
    float* f16b  = f16a + (size_t)N * 16;           // N*16
    float* f32a  = f16b + (size_t)N * 16;           // N*32
    float* f32b  = f32a + (size_t)N * 32;           // N*32
    unsigned* pooled = (unsigned*)(f32b + (size_t)N * 32);  // 512
    // part aliases f32a region (dead before any f32 use); E=3.2M <= 32N=3.2M ok
    int* part = (int*)f32a;
    float* f64 = f16a;                              // 64N spans f16a..f32a end
    float* f4a = f32b;                              // after L3 matmul, f32b free
    float* f4b = f32b + (size_t)N * 4;

    const int B = 256;
    const int gridN = DIV_UP(N, B);

    // CSR build: hist -> scan -> batched partition -> per-bucket finalize (emits dinv too)
    zero_int_k<<<DIV_UP(1024, B), B, 0, stream>>>(bhist, 1024);
    bucket_hist_k<<<512, B, 0, stream>>>(col, bhist, E, NB);
    bucket_scan_k<<<1, 256, 0, stream>>>(bhist, bcur, NB);
    partition_k<<<DIV_UP(E, CHUNK_E), B, 0, stream>>>(row, col, bcur, part, E, NB);
    csr_build_k<<<NB, B, 0, stream>>>(part, bcur, cur, dinv, csr, N);

    // L1: y1 = (x@W1)*dinv -> f16b ; gather+bias+relu+scale -> f16a
    matmul_k<128,16,false,false,true><<<gridN, B, 0, stream>>>(x, W1, nullptr, dinv, f16b, N);
    gather_prop_k<16,1><<<DIV_UP(N*4, B), B, 0, stream>>>(f16b, dinv, cur, csr, b1, f16a, N);

    // L2: gather f16a -> f16b (raw agg) ; matmul 16->32 +b2,relu,*dinv -> f32a
    gather_prop_k<16,0><<<DIV_UP(N*4, B), B, 0, stream>>>(f16a, dinv, cur, csr, nullptr, f16b, N);
    matmul_k<16,32,true,true,true><<<gridN, B, 0, stream>>>(f16b, W2, b2, dinv, f32a, N);

    // L3: gather f32a -> f32b ; matmul 32->64 +b3,relu,*dinv -> f64 (= f16a..f32a)
    gather_prop_k<32,0><<<DIV_UP(N*8, B), B, 0, stream>>>(f32a, dinv, cur, csr, nullptr, f32b, N);
    matmul_k<32,64,true,true,true><<<gridN, B, 0, stream>>>(f32b, W3, b3, dinv, f64, N);

    // L4: y4 = h3s@W4 (already dinv-scaled input) -> f4a ; gather raw -> f4b
    matmul_k<64,4,false,false,false><<<gridN, B, 0, stream>>>(f64, W4, nullptr, nullptr, f4a, N);
    gather_prop_k<4,0><<<DIV_UP(N, B), B, 0, stream>>>(f4a, dinv, cur, csr, nullptr, f4b, N);

    // pool (adds b4) + log_softmax
    pool_init_k<<<DIV_UP(G*4, B), B, 0, stream>>>(pooled, G*4);
    pool_max_k<<<gridN, B, 0, stream>>>(f4b, b4, batch, pooled, N, G);
    logsoftmax_k<<<1, 128, 0, stream>>>(pooled, (float*)d_out, G);
}

// Round 5
// 344.899 us; speedup vs baseline: 3.6703x; 1.7272x over previous
//
#include <hip/hip_runtime.h>

#define DIV_UP(a,b) (((a)+(b)-1)/(b))

// bucket = tgt >> 7  (128 nodes per bucket)
constexpr int BSHIFT = 7;
constexpr int BNODES = 128;
constexpr int CHUNK_E = 16384;   // edges per partition block

// ---------------- CSR build via bucket counting sort ----------------
__global__ void zero_int_k(int* p, int n) {
    int i = blockIdx.x * blockDim.x + threadIdx.x;
    if (i < n) p[i] = 0;
}

__global__ void bucket_hist_k(const int* __restrict__ col, int* __restrict__ bhist, int E, int nb) {
    __shared__ int lh[1024];
    for (int i = threadIdx.x; i < 1024; i += blockDim.x) lh[i] = 0;
    __syncthreads();
    int stride = gridDim.x * blockDim.x;
    for (int e = blockIdx.x * blockDim.x + threadIdx.x; e < E; e += stride)
        atomicAdd(&lh[col[e] >> BSHIFT], 1);
    __syncthreads();
    for (int i = threadIdx.x; i < nb; i += blockDim.x) {
        int v = lh[i];
        if (v) atomicAdd(&bhist[i], v);
    }
}

// exclusive scan of nb (<=1024) bucket counts -> bcur
__global__ void bucket_scan_k(const int* __restrict__ bhist, int* __restrict__ bcur, int nb) {
    __shared__ int lds[256];
    int base = threadIdx.x * 4;
    int v[4]; int s = 0;
#pragma unroll
    for (int j = 0; j < 4; j++) { v[j] = (base + j < nb) ? bhist[base + j] : 0; s += v[j]; }
    lds[threadIdx.x] = s; __syncthreads();
    for (int off = 1; off < 256; off <<= 1) {
        int t = (threadIdx.x >= off) ? lds[threadIdx.x - off] : 0;
        __syncthreads();
        lds[threadIdx.x] += t;
        __syncthreads();
    }
    int excl = lds[threadIdx.x] - s;
#pragma unroll
    for (int j = 0; j < 4; j++) {
        if (base + j < nb) bcur[base + j] = excl;
        excl += v[j];
    }
}

// block-batched partition: LDS histogram -> bulk range reservation -> LDS-cursor scatter
// pack (src<<7)|(tgt&127) in 4B (src < 2^17 ok: N=100000 < 131072)
__global__ void partition_k(const int* __restrict__ row, const int* __restrict__ col,
                            int* __restrict__ bcur, int* __restrict__ part, int E, int nb) {
    __shared__ int lh[1024];
    for (int i = threadIdx.x; i < nb; i += blockDim.x) lh[i] = 0;
    __syncthreads();
    int base = blockIdx.x * CHUNK_E;
    int end = min(E, base + CHUNK_E);
    for (int e = base + threadIdx.x; e < end; e += blockDim.x)
        atomicAdd(&lh[col[e] >> BSHIFT], 1);
    __syncthreads();
    for (int i = threadIdx.x; i < nb; i += blockDim.x) {
        int c = lh[i];
        lh[i] = c ? atomicAdd(&bcur[i], c) : 0;   // reserve dense run, LDS keeps base cursor
    }
    __syncthreads();
    for (int e = base + threadIdx.x; e < end; e += blockDim.x) {
        int r = row[e], c = col[e];
        int p = atomicAdd(&lh[c >> BSHIFT], 1);
        part[p] = (r << BSHIFT) | (c & (BNODES - 1));
    }
}

// one block per bucket: count local degrees, scan, emit dinv/cur, scatter csr
__global__ void csr_build_k(const int* __restrict__ part, const int* __restrict__ bcur,
                            int* __restrict__ cur, float* __restrict__ dinv,
                            int* __restrict__ csr, int N) {
    __shared__ int ldeg[BNODES];
    __shared__ int lofs[BNODES];
    __shared__ int ebounds[2];
    int b = blockIdx.x;
    int tid = threadIdx.x;
    if (tid == 0) { ebounds[0] = b ? bcur[b - 1] : 0; ebounds[1] = bcur[b]; }
    if (tid < BNODES) ldeg[tid] = 0;
    __syncthreads();
    int e0 = ebounds[0], e1 = ebounds[1];
    for (int e = e0 + tid; e < e1; e += blockDim.x)
        atomicAdd(&ldeg[part[e] & (BNODES - 1)], 1);
    __syncthreads();
    if (tid < BNODES) lofs[tid] = ldeg[tid];
    __syncthreads();
    for (int off = 1; off < BNODES; off <<= 1) {
        int t = (tid >= off && tid < BNODES) ? lofs[tid - off] : 0;
        __syncthreads();
        if (tid < BNODES) lofs[tid] += t;
        __syncthreads();
    }
    if (tid < BNODES) {
        int node = b * BNODES + tid;
        int d = ldeg[tid];
        int incl = lofs[tid];
        if (node < N) {
            cur[node] = e0 + incl;                       // inclusive end
            dinv[node] = rsqrtf(1.0f + (float)d);        // +1 self loop
        }
        ldeg[tid] = e0 + incl - d;                       // becomes write cursor
    }
    __syncthreads();
    for (int e = e0 + tid; e < e1; e += blockDim.x) {
        int v = part[e];
        int p = atomicAdd(&ldeg[v & (BNODES - 1)], 1);
        csr[p] = v >> BSHIFT;
    }
}

// ---------------- gather propagation (inputs pre-scaled by dinv) ----------------
// out_raw = dinv[t] * ( hs[t] + sum_{edges} hs[src] )   == (D^-1/2 A_hat D^-1/2 h)[t]
// EPI 0: store out_raw.   EPI 1: store relu(out_raw + b) * dinv[t]  (ready for next layer)
template<int D, int EPI>
__global__ void gather_prop_k(const float* __restrict__ hs, const float* __restrict__ dinv,
                              const int* __restrict__ cur, const int* __restrict__ csr,
                              const float* __restrict__ b, float* __restrict__ out, int n) {
    constexpr int TPN = D / 4;
    int tid = blockIdx.x * blockDim.x + threadIdx.x;
    int node = tid / TPN, t = tid % TPN;
    if (node >= n) return;
    float di = dinv[node];
    float4 acc = reinterpret_cast<const float4*>(hs + (size_t)node * D)[t];
    int e0 = node ? cur[node - 1] : 0;
    int e1 = cur[node];
    int e = e0;
    for (; e + 1 < e1; e += 2) {
        int s0 = csr[e], s1 = csr[e + 1];
        float4 v0 = reinterpret_cast<const float4*>(hs + (size_t)s0 * D)[t];
        float4 v1 = reinterpret_cast<const float4*>(hs + (size_t)s1 * D)[t];
        acc.x += v0.x + v1.x; acc.y += v0.y + v1.y;
        acc.z += v0.z + v1.z; acc.w += v0.w + v1.w;
    }
    if (e < e1) {
        int s0 = csr[e];
        float4 v0 = reinterpret_cast<const float4*>(hs + (size_t)s0 * D)[t];
        acc.x += v0.x; acc.y += v0.y; acc.z += v0.z; acc.w += v0.w;
    }
    acc.x *= di; acc.y *= di; acc.z *= di; acc.w *= di;
    if (EPI == 1) {
        acc.x = fmaxf(acc.x + b[t*4+0], 0.f) * di;
        acc.y = fmaxf(acc.y + b[t*4+1], 0.f) * di;
        acc.z = fmaxf(acc.z + b[t*4+2], 0.f) * di;
        acc.w = fmaxf(acc.w + b[t*4+3], 0.f) * di;
    }
    reinterpret_cast<float4*>(out + (size_t)node * D)[t] = acc;
}

// ---------------- LDS-tiled skinny matmul: y[n,OUT] = x[n,IN] @ W (+b, relu, *dinv) ----
// 64-node tile staged in LDS (coalesced float4 loads), 4 threads/node, each produces
// OUT/4 contiguous outputs (coalesced float4 stores). Row pad +4 floats vs bank conflicts.
template<int IN, int OUT, bool RELU, bool BIAS, bool SCALE>
__global__ void __launch_bounds__(256) matmul_k(
        const float* __restrict__ x, const float* __restrict__ W,
        const float* __restrict__ b, const float* __restrict__ dinv,
        float* __restrict__ y, int n) {
    constexpr int TN  = 64;           // nodes per block
    constexpr int RS  = IN + 4;       // padded row stride (multiple of 4 -> float4 aligned)
    constexpr int OPT = OUT / 4;      // outputs per thread (4 threads per node)
    constexpr int NQ  = IN / 4;       // float4 per row
    __shared__ float xs[TN * RS];
    __shared__ float Ws[IN * OUT];
    __shared__ float bs[OUT];

    for (int i = threadIdx.x; i < IN * OUT; i += 256) Ws[i] = W[i];
    if (BIAS) for (int i = threadIdx.x; i < OUT; i += 256) bs[i] = b[i];

    int base = blockIdx.x * TN;
    for (int i = threadIdx.x; i < TN * NQ; i += 256) {
        int r = i / NQ, c = i % NQ;
        float4 v = make_float4(0.f, 0.f, 0.f, 0.f);
        if (base + r < n) v = reinterpret_cast<const float4*>(x + (size_t)(base + r) * IN)[c];
        *reinterpret_cast<float4*>(&xs[r * RS + c * 4]) = v;
    }
    __syncthreads();

    int node = threadIdx.x >> 2;          // 0..63
    int g    = threadIdx.x & 3;           // 0..3
    int j0   = g * OPT;
    if (base + node >= n) return;

    float acc[OPT];
#pragma unroll
    for (int jj = 0; jj < OPT; jj++) acc[jj] = 0.f;

    const float* xrow = &xs[node * RS];
#pragma unroll
    for (int k4 = 0; k4 < NQ; k4++) {
        float4 xv = *reinterpret_cast<const float4*>(&xrow[k4 * 4]);
        float xk[4] = {xv.x, xv.y, xv.z, xv.w};
#pragma unroll
        for (int kk = 0; kk < 4; kk++) {
            const float* wrow = &Ws[(k4 * 4 + kk) * OUT + j0];
#pragma unroll
            for (int jj = 0; jj < OPT; jj++)
                acc[jj] += xk[kk] * wrow[jj];
        }
    }

    float di = SCALE ? dinv[base + node] : 1.f;
    float vout[OPT];
#pragma unroll
    for (int jj = 0; jj < OPT; jj++) {
        float v = acc[jj] + (BIAS ? bs[j0 + jj] : 0.f);
        if (RELU) v = fmaxf(v, 0.f);
        if (SCALE) v *= di;
        vout[jj] = v;
    }
    float* yr = y + (size_t)(base + node) * OUT + j0;
    if (OPT % 4 == 0) {
#pragma unroll
        for (int q = 0; q < OPT / 4; q++)
            *reinterpret_cast<float4*>(yr + q * 4) =
                make_float4(vout[q*4+0], vout[q*4+1], vout[q*4+2], vout[q*4+3]);
    } else {
#pragma unroll
        for (int jj = 0; jj < OPT; jj++) yr[jj] = vout[jj];
    }
}

// ---------------- pooling + log_softmax ----------------
__device__ inline unsigned fkey(float x) {
    unsigned u = __float_as_uint(x);
    return (u & 0x80000000u) ? ~u : (u | 0x80000000u);
}
__device__ inline float funkey(unsigned k) {
    unsigned u = (k & 0x80000000u) ? (k & 0x7FFFFFFFu) : ~k;
    return __uint_as_float(u);
}

__global__ void pool_init_k(unsigned* pooled, int total) {
    int i = blockIdx.x * blockDim.x + threadIdx.x;
    if (i < total) pooled[i] = 0u;
}

__global__ void pool_max_k(const float* __restrict__ h4, const float* __restrict__ b4,
                           const int* __restrict__ batch, unsigned* __restrict__ pooled,
                           int n, int num_graphs) {
    __shared__ unsigned lds[128 * 4];
    for (int i = threadIdx.x; i < num_graphs * 4; i += blockDim.x) lds[i] = 0u;
    __syncthreads();
    int i = blockIdx.x * blockDim.x + threadIdx.x;
    if (i < n) {
        int g = batch[i];
        float4 v = reinterpret_cast<const float4*>(h4)[i];
        atomicMax(&lds[g*4+0], fkey(v.x + b4[0]));
        atomicMax(&lds[g*4+1], fkey(v.y + b4[1]));
        atomicMax(&lds[g*4+2], fkey(v.z + b4[2]));
        atomicMax(&lds[g*4+3], fkey(v.w + b4[3]));
    }
    __syncthreads();
    for (int i2 = threadIdx.x; i2 < num_graphs * 4; i2 += blockDim.x) {
        unsigned k = lds[i2];
        if (k) atomicMax(&pooled[i2], k);
    }
}

__global__ void logsoftmax_k(const unsigned* __restrict__ pooled, float* __restrict__ out, int G) {
    int g = blockIdx.x * blockDim.x + threadIdx.x;
    if (g >= G) return;
    float v[4];
#pragma unroll
    for (int j = 0; j < 4; j++) v[j] = funkey(pooled[g*4+j]);
    float m = fmaxf(fmaxf(v[0], v[1]), fmaxf(v[2], v[3]));
    float s = 0.f;
#pragma unroll
    for (int j = 0; j < 4; j++) s += expf(v[j] - m);
    float l = logf(s);
#pragma unroll
    for (int j = 0; j < 4; j++) out[g*4+j] = v[j] - m - l;
}

// ---------------- launch ----------------
extern "C" void kernel_launch(void* const* d_in, const int* in_sizes, int n_in,
                              void* d_out, int out_size, void* d_ws, size_t ws_size,
                              hipStream_t stream) {
    const float* x     = (const float*)d_in[0];
    const int*   ei    = (const int*)d_in[1];
    const int*   batch = (const int*)d_in[2];
    const float* W1 = (const float*)d_in[3];
    const float* b1 = (const float*)d_in[4];
    const float* W2 = (const float*)d_in[5];
    const float* b2 = (const float*)d_in[6];
    const float* W3 = (const float*)d_in[7];
    const float* b3 = (const float*)d_in[8];
    const float* W4 = (const float*)d_in[9];
    const float* b4 = (const float*)d_in[10];

    const int N = in_sizes[2];          // 100000
    const int E = in_sizes[1] / 2;      // 3.2M
    const int G = 128;
    const int* row = ei;
    const int* col = ei + E;
    const int NB = DIV_UP(N, BNODES);   // 782 buckets

    // workspace layout
    float* ws    = (float*)d_ws;
    float* dinv  = ws;                              // N floats
    int*   cur   = (int*)(dinv + N);                // N ints (inclusive seg ends)
    int*   bhist = cur + N;                         // 1024 ints
    int*   bcur  = bhist + 1024;                    // 1024 ints
    int*   csr   = bcur + 1024;                     // E ints
    float* f16a  = (float*)(csr + E);               // N*16
    float* f16b  = f16a + (size_t)N * 16;           // N*16
    float* f32a  = f16b + (size_t)N * 16;           // N*32
    float* f32b  = f32a + (size_t)N * 32;           // N*32
    unsigned* pooled = (unsigned*)(f32b + (size_t)N * 32);  // 512
    // part aliases f32a region (dead before any f32 use); E=3.2M <= 32N=3.2M ok
    int* part = (int*)f32a;
    float* f64 = f16a;                              // 64N spans f16a..f32a end
    float* f4a = f32b;                              // after L3 matmul, f32b free
    float* f4b = f32b + (size_t)N * 4;

    const int B = 256;
    const int gridN = DIV_UP(N, B);
    const int gridM = DIV_UP(N, 64);    // tiled matmul: 64 nodes/block

    // CSR build: hist -> scan -> batched partition -> per-bucket finalize (emits dinv too)
    zero_int_k<<<DIV_UP(1024, B), B, 0, stream>>>(bhist, 1024);
    bucket_hist_k<<<512, B, 0, stream>>>(col, bhist, E, NB);
    bucket_scan_k<<<1, 256, 0, stream>>>(bhist, bcur, NB);
    partition_k<<<DIV_UP(E, CHUNK_E), B, 0, stream>>>(row, col, bcur, part, E, NB);
    csr_build_k<<<NB, B, 0, stream>>>(part, bcur, cur, dinv, csr, N);

    // L1: y1 = (x@W1)*dinv -> f16b ; gather+bias+relu+scale -> f16a
    matmul_k<128,16,false,false,true><<<gridM, B, 0, stream>>>(x, W1, nullptr, dinv, f16b, N);
    gather_prop_k<16,1><<<DIV_UP(N*4, B), B, 0, stream>>>(f16b, dinv, cur, csr, b1, f16a, N);

    // L2: gather f16a -> f16b (raw agg) ; matmul 16->32 +b2,relu,*dinv -> f32a
    gather_prop_k<16,0><<<DIV_UP(N*4, B), B, 0, stream>>>(f16a, dinv, cur, csr, nullptr, f16b, N);
    matmul_k<16,32,true,true,true><<<gridM, B, 0, stream>>>(f16b, W2, b2, dinv, f32a, N);

    // L3: gather f32a -> f32b ; matmul 32->64 +b3,relu,*dinv -> f64 (= f16a..f32a)
    gather_prop_k<32,0><<<DIV_UP(N*8, B), B, 0, stream>>>(f32a, dinv, cur, csr, nullptr, f32b, N);
    matmul_k<32,64,true,true,true><<<gridM, B, 0, stream>>>(f32b, W3, b3, dinv, f64, N);

    // L4: y4 = h3s@W4 (already dinv-scaled input) -> f4a ; gather raw -> f4b
    matmul_k<64,4,false,false,false><<<gridM, B, 0, stream>>>(f64, W4, nullptr, nullptr, f4a, N);
    gather_prop_k<4,0><<<DIV_UP(N, B), B, 0, stream>>>(f4a, dinv, cur, csr, nullptr, f4b, N);

    // pool (adds b4) + log_softmax
    pool_init_k<<<DIV_UP(G*4, B), B, 0, stream>>>(pooled, G*4);
    pool_max_k<<<gridN, B, 0, stream>>>(f4b, b4, batch, pooled, N, G);
    logsoftmax_k<<<1, 128, 0, stream>>>(pooled, (float*)d_out, G);
}